// Round 1
// baseline (107.661 us; speedup 1.0000x reference)
//
#include <hip/hip_runtime.h>

#define BB 16
#define QQ 64
#define KK 512
#define DD 256
#define HH 256
#define QT 4      // q rows per scores block
#define KSPL 4    // k-splits for scores grid

// tanh(x) = 1 - 2/(e^{2x}+1); exact at both saturation ends (exp->0 or inf)
__device__ __forceinline__ float tanh_fast(float x) {
    float e = __expf(2.0f * x);
    return 1.0f - 2.0f * __builtin_amdgcn_rcpf(e + 1.0f);
}

// ---------------------------------------------------------------------------
// Y[N][256] = X[N][256] @ W[256][256], f32, 64x64 tile, 256 thr, 4x4/thread
// ---------------------------------------------------------------------------
__global__ __launch_bounds__(256) void proj_gemm(const float* __restrict__ X,
                                                 const float* __restrict__ W,
                                                 float* __restrict__ Y) {
    __shared__ float Xs[64][17];   // padded: read Xs[m][kk] conflict-free
    __shared__ float Ws[16][64];
    const int tid = threadIdx.x;
    const int tx = tid & 15, ty = tid >> 4;
    const int row0 = blockIdx.x * 64;
    const int col0 = blockIdx.y * 64;

    float acc[4][4] = {};

    for (int k0 = 0; k0 < HH; k0 += 16) {
        {   // stage X tile: 64 rows x 16 k
            int m = tid >> 2, kk = (tid & 3) * 4;
            float4 x4 = *(const float4*)(X + (size_t)(row0 + m) * HH + k0 + kk);
            Xs[m][kk+0] = x4.x; Xs[m][kk+1] = x4.y;
            Xs[m][kk+2] = x4.z; Xs[m][kk+3] = x4.w;
        }
        {   // stage W tile: 16 k x 64 cols
            int kk = tid >> 4, c = (tid & 15) * 4;
            float4 w4 = *(const float4*)(W + (size_t)(k0 + kk) * HH + col0 + c);
            *(float4*)(&Ws[kk][c]) = w4;
        }
        __syncthreads();
        #pragma unroll
        for (int kk = 0; kk < 16; ++kk) {
            float a0 = Xs[ty*4+0][kk], a1 = Xs[ty*4+1][kk];
            float a2 = Xs[ty*4+2][kk], a3 = Xs[ty*4+3][kk];
            float4 b4 = *(const float4*)(&Ws[kk][tx*4]);
            acc[0][0] += a0*b4.x; acc[0][1] += a0*b4.y; acc[0][2] += a0*b4.z; acc[0][3] += a0*b4.w;
            acc[1][0] += a1*b4.x; acc[1][1] += a1*b4.y; acc[1][2] += a1*b4.z; acc[1][3] += a1*b4.w;
            acc[2][0] += a2*b4.x; acc[2][1] += a2*b4.y; acc[2][2] += a2*b4.z; acc[2][3] += a2*b4.w;
            acc[3][0] += a3*b4.x; acc[3][1] += a3*b4.y; acc[3][2] += a3*b4.z; acc[3][3] += a3*b4.w;
        }
        __syncthreads();
    }
    #pragma unroll
    for (int i = 0; i < 4; ++i) {
        float4 o = make_float4(acc[i][0], acc[i][1], acc[i][2], acc[i][3]);
        *(float4*)(Y + (size_t)(row0 + ty*4 + i) * HH + col0 + tx*4) = o;
    }
}

// ---------------------------------------------------------------------------
// scores[b,q,k] = sum_h w_v[h]*tanh(qf[b,q,h] + kf[b,k,h]); masked to -1e6
// grid (B, Q/QT, KSPL), block 256. Lane l owns h = 4l..4l+3 in registers.
// Wave w handles 32 consecutive k of its 128-k split.
// ---------------------------------------------------------------------------
__global__ __launch_bounds__(256) void scores_kernel(
        const float* __restrict__ qf, const float* __restrict__ kf,
        const float* __restrict__ w_v, const int* __restrict__ valid_lens,
        float* __restrict__ scores) {
    const int b    = blockIdx.x;
    const int qt   = blockIdx.y;
    const int ks   = blockIdx.z;
    const int lane = threadIdx.x & 63;
    const int wave = threadIdx.x >> 6;
    const int h    = lane * 4;

    const float4 wv = *(const float4*)(w_v + h);
    float4 qv[QT];
    #pragma unroll
    for (int j = 0; j < QT; ++j)
        qv[j] = *(const float4*)(qf + (size_t)(b*QQ + qt*QT + j) * HH + h);

    const int vl = valid_lens[b];
    const int kbase = ks * (KK / KSPL) + wave * (KK / KSPL / 4);

    for (int i = 0; i < KK / KSPL / 4; ++i) {
        const int k = kbase + i;
        const float4 kv = *(const float4*)(kf + (size_t)(b*KK + k) * HH + h);
        float s[QT];
        #pragma unroll
        for (int j = 0; j < QT; ++j) {
            s[j] = wv.x * tanh_fast(qv[j].x + kv.x)
                 + wv.y * tanh_fast(qv[j].y + kv.y)
                 + wv.z * tanh_fast(qv[j].z + kv.z)
                 + wv.w * tanh_fast(qv[j].w + kv.w);
        }
        #pragma unroll
        for (int j = 0; j < QT; ++j) {
            #pragma unroll
            for (int off = 32; off > 0; off >>= 1)
                s[j] += __shfl_xor(s[j], off);
        }
        if (lane == 0) {
            #pragma unroll
            for (int j = 0; j < QT; ++j)
                scores[(size_t)(b*QQ + qt*QT + j) * KK + k] = (k < vl) ? s[j] : -1e6f;
        }
    }
}

// ---------------------------------------------------------------------------
// softmax over K then out[b,q,:] = attn @ values[b]
// grid (B, Q/4), block 256: wave w owns row q = qt*4+w (softmax + 64*4 d cols)
// ---------------------------------------------------------------------------
__global__ __launch_bounds__(256) void attn_pv_kernel(
        const float* __restrict__ scores, const float* __restrict__ values,
        float* __restrict__ out) {
    __shared__ float p[4][KK];
    const int b    = blockIdx.x;
    const int qt   = blockIdx.y;
    const int lane = threadIdx.x & 63;
    const int wave = threadIdx.x >> 6;
    const int q    = qt * 4 + wave;

    const float* srow = scores + (size_t)(b*QQ + q) * KK;
    float4 s0 = *(const float4*)(srow + lane*8);
    float4 s1 = *(const float4*)(srow + lane*8 + 4);

    float m = fmaxf(fmaxf(fmaxf(s0.x, s0.y), fmaxf(s0.z, s0.w)),
                    fmaxf(fmaxf(s1.x, s1.y), fmaxf(s1.z, s1.w)));
    #pragma unroll
    for (int off = 32; off > 0; off >>= 1)
        m = fmaxf(m, __shfl_xor(m, off));

    float e[8];
    e[0] = __expf(s0.x - m); e[1] = __expf(s0.y - m);
    e[2] = __expf(s0.z - m); e[3] = __expf(s0.w - m);
    e[4] = __expf(s1.x - m); e[5] = __expf(s1.y - m);
    e[6] = __expf(s1.z - m); e[7] = __expf(s1.w - m);
    float sum = ((e[0]+e[1]) + (e[2]+e[3])) + ((e[4]+e[5]) + (e[6]+e[7]));
    #pragma unroll
    for (int off = 32; off > 0; off >>= 1)
        sum += __shfl_xor(sum, off);
    const float inv = 1.0f / sum;

    float4 p0 = make_float4(e[0]*inv, e[1]*inv, e[2]*inv, e[3]*inv);
    float4 p1 = make_float4(e[4]*inv, e[5]*inv, e[6]*inv, e[7]*inv);
    *(float4*)(&p[wave][lane*8])     = p0;
    *(float4*)(&p[wave][lane*8 + 4]) = p1;
    __syncthreads();

    const int d = lane * 4;
    const float* V = values + (size_t)b * KK * DD;
    float4 acc = make_float4(0.f, 0.f, 0.f, 0.f);
    #pragma unroll 8
    for (int k = 0; k < KK; ++k) {
        float4 v4 = *(const float4*)(V + (size_t)k * DD + d);
        float pw = p[wave][k];
        acc.x += pw * v4.x; acc.y += pw * v4.y;
        acc.z += pw * v4.z; acc.w += pw * v4.w;
    }
    *(float4*)(out + (size_t)(b*QQ + q) * DD + d) = acc;
}

extern "C" void kernel_launch(void* const* d_in, const int* in_sizes, int n_in,
                              void* d_out, int out_size, void* d_ws, size_t ws_size,
                              hipStream_t stream) {
    (void)in_sizes; (void)n_in; (void)out_size; (void)ws_size;
    const float* querys     = (const float*)d_in[0];
    const float* keys       = (const float*)d_in[1];
    const float* values     = (const float*)d_in[2];
    const int*   valid_lens = (const int*)d_in[3];
    const float* Wq         = (const float*)d_in[4];
    const float* Wk         = (const float*)d_in[5];
    const float* w_v        = (const float*)d_in[6];
    float* out = (float*)d_out;

    float* qf     = (float*)d_ws;                      // 16*64*256  f32 = 1 MB
    float* kfeat  = qf + (size_t)BB*QQ*HH;             // 16*512*256 f32 = 8 MB
    float* scores = kfeat + (size_t)BB*KK*HH;          // 16*64*512  f32 = 2 MB

    proj_gemm<<<dim3(BB*QQ/64, HH/64), 256, 0, stream>>>(querys, Wq, qf);
    proj_gemm<<<dim3(BB*KK/64, HH/64), 256, 0, stream>>>(keys, Wk, kfeat);
    scores_kernel<<<dim3(BB, QQ/QT, KSPL), 256, 0, stream>>>(qf, kfeat, w_v, valid_lens, scores);
    attn_pv_kernel<<<dim3(BB, QQ/4), 256, 0, stream>>>(scores, values, out);
}

// Round 2
// 85.632 us; speedup vs baseline: 1.2573x; 1.2573x over previous
//
#include <hip/hip_runtime.h>

#define BB 16
#define QQ 64
#define KK 512
#define DD 256
#define HH 256
#define KSPL 4

#define LOG2E2 2.88539008177792681f   // 2*log2(e): exp2(LOG2E2*x) = e^{2x}

__device__ __forceinline__ float fast_exp2(float x) {
#if __has_builtin(__builtin_amdgcn_exp2f)
    return __builtin_amdgcn_exp2f(x);
#else
    return exp2f(x);
#endif
}

// ---------------------------------------------------------------------------
// Both projections in one launch. Y = (X @ W) * 2log2e.
// 64x64 tile, 256 thr, 4x4/thread, K-step 32, A transposed in LDS (b128 reads).
// grid.x: tiles 0..15 -> query rows (1024), 16..143 -> key rows (8192)
// ---------------------------------------------------------------------------
__global__ __launch_bounds__(256) void proj_both(
        const float* __restrict__ Xq, const float* __restrict__ Wq, float* __restrict__ Yq,
        const float* __restrict__ Xk, const float* __restrict__ Wk, float* __restrict__ Yk) {
    __shared__ float XsT[32][68];   // stride 272B: 16B-aligned rows, broadcast reads
    __shared__ float Ws[32][64];
    const int rt = blockIdx.x;
    const float* X; const float* W; float* Y; int row0;
    if (rt < 16) { X = Xq; W = Wq; Y = Yq; row0 = rt * 64; }
    else         { X = Xk; W = Wk; Y = Yk; row0 = (rt - 16) * 64; }
    const int col0 = blockIdx.y * 64;
    const int tid = threadIdx.x;
    const int tx = tid & 15, ty = tid >> 4;

    float acc[4][4] = {};

    for (int k0 = 0; k0 < HH; k0 += 32) {
        {   // stage X tile 64 rows x 32 k, transposed
            const int m  = tid >> 3;
            const int kk = (tid & 7) * 4;
            #pragma unroll
            for (int s = 0; s < 2; ++s) {
                float4 x4 = *(const float4*)(X + (size_t)(row0 + m + 32*s) * HH + k0 + kk);
                XsT[kk+0][m+32*s] = x4.x;
                XsT[kk+1][m+32*s] = x4.y;
                XsT[kk+2][m+32*s] = x4.z;
                XsT[kk+3][m+32*s] = x4.w;
            }
        }
        {   // stage W tile 32 k x 64 cols
            const int kk = tid >> 4;
            const int c  = (tid & 15) * 4;
            #pragma unroll
            for (int s = 0; s < 2; ++s) {
                float4 w4 = *(const float4*)(W + (size_t)(k0 + kk + 16*s) * HH + col0 + c);
                *(float4*)(&Ws[kk+16*s][c]) = w4;
            }
        }
        __syncthreads();
        #pragma unroll
        for (int kk = 0; kk < 32; ++kk) {
            float4 a = *(const float4*)(&XsT[kk][ty*4]);
            float4 b = *(const float4*)(&Ws[kk][tx*4]);
            acc[0][0] += a.x*b.x; acc[0][1] += a.x*b.y; acc[0][2] += a.x*b.z; acc[0][3] += a.x*b.w;
            acc[1][0] += a.y*b.x; acc[1][1] += a.y*b.y; acc[1][2] += a.y*b.z; acc[1][3] += a.y*b.w;
            acc[2][0] += a.z*b.x; acc[2][1] += a.z*b.y; acc[2][2] += a.z*b.z; acc[2][3] += a.z*b.w;
            acc[3][0] += a.w*b.x; acc[3][1] += a.w*b.y; acc[3][2] += a.w*b.z; acc[3][3] += a.w*b.w;
        }
        __syncthreads();
    }
    #pragma unroll
    for (int i = 0; i < 4; ++i) {
        float4 o = make_float4(acc[i][0]*LOG2E2, acc[i][1]*LOG2E2,
                               acc[i][2]*LOG2E2, acc[i][3]*LOG2E2);
        *(float4*)(Y + (size_t)(row0 + ty*4 + i) * HH + col0 + tx*4) = o;
    }
}

// ---------------------------------------------------------------------------
// scores[b,q,k] = sum_h wv_h * tanh(...) with inputs pre-scaled by 2log2e:
//   tanh = 1 - 2/(1 + exp2(qs+ks));  score = sum(wv) - sum(2*wv/(1+e))
// Lane layout: hg = lane&15 owns h-chunk [hg*16, hg*16+16); ksub = lane>>4.
// Each wave step: 4 k's; reduce = 4-stage shfl within 16-lane groups.
// grid (B, Q, KSPL), block 256 (4 waves); wave handles 32 k = 8 groups.
// ---------------------------------------------------------------------------
__global__ __launch_bounds__(256) void scores_kernel(
        const float* __restrict__ qf, const float* __restrict__ kf,
        const float* __restrict__ w_v, const int* __restrict__ valid_lens,
        float* __restrict__ scores) {
    const int b    = blockIdx.x;
    const int q    = blockIdx.y;
    const int ks   = blockIdx.z;
    const int lane = threadIdx.x & 63;
    const int wave = threadIdx.x >> 6;
    const int hg   = lane & 15;
    const int ksub = lane >> 4;
    const int h0   = hg * 16;

    float4 w0 = *(const float4*)(w_v + h0);
    float4 w1 = *(const float4*)(w_v + h0 + 4);
    float4 w2 = *(const float4*)(w_v + h0 + 8);
    float4 w3 = *(const float4*)(w_v + h0 + 12);
    const float wvsum = ((w0.x+w0.y)+(w0.z+w0.w)) + ((w1.x+w1.y)+(w1.z+w1.w))
                      + ((w2.x+w2.y)+(w2.z+w2.w)) + ((w3.x+w3.y)+(w3.z+w3.w));
    const float4 n0 = make_float4(-2.f*w0.x, -2.f*w0.y, -2.f*w0.z, -2.f*w0.w);
    const float4 n1 = make_float4(-2.f*w1.x, -2.f*w1.y, -2.f*w1.z, -2.f*w1.w);
    const float4 n2 = make_float4(-2.f*w2.x, -2.f*w2.y, -2.f*w2.z, -2.f*w2.w);
    const float4 n3 = make_float4(-2.f*w3.x, -2.f*w3.y, -2.f*w3.z, -2.f*w3.w);

    const float* qrow = qf + (size_t)(b*QQ + q) * HH + h0;
    const float4 q0 = *(const float4*)(qrow);
    const float4 q1 = *(const float4*)(qrow + 4);
    const float4 q2 = *(const float4*)(qrow + 8);
    const float4 q3 = *(const float4*)(qrow + 12);

    const int vl = valid_lens[b];
    const int kbase = ks * (KK/KSPL) + wave * (KK/KSPL/4) + ksub;
    float* srow = scores + (size_t)(b*QQ + q) * KK;

    for (int g = 0; g < KK/KSPL/4/4; ++g) {
        const int k = kbase + g * 4;
        const float* krow = kf + (size_t)(b*KK + k) * HH + h0;
        const float4 k0 = *(const float4*)(krow);
        const float4 k1 = *(const float4*)(krow + 4);
        const float4 k2 = *(const float4*)(krow + 8);
        const float4 k3 = *(const float4*)(krow + 12);

        float a0 = wvsum, a1 = 0.f, a2 = 0.f, a3 = 0.f;
        {
            float e0 = fast_exp2(q0.x + k0.x), e1 = fast_exp2(q0.y + k0.y);
            float e2 = fast_exp2(q0.z + k0.z), e3 = fast_exp2(q0.w + k0.w);
            a0 = fmaf(n0.x, __builtin_amdgcn_rcpf(e0 + 1.f), a0);
            a1 = fmaf(n0.y, __builtin_amdgcn_rcpf(e1 + 1.f), a1);
            a2 = fmaf(n0.z, __builtin_amdgcn_rcpf(e2 + 1.f), a2);
            a3 = fmaf(n0.w, __builtin_amdgcn_rcpf(e3 + 1.f), a3);
        }
        {
            float e0 = fast_exp2(q1.x + k1.x), e1 = fast_exp2(q1.y + k1.y);
            float e2 = fast_exp2(q1.z + k1.z), e3 = fast_exp2(q1.w + k1.w);
            a0 = fmaf(n1.x, __builtin_amdgcn_rcpf(e0 + 1.f), a0);
            a1 = fmaf(n1.y, __builtin_amdgcn_rcpf(e1 + 1.f), a1);
            a2 = fmaf(n1.z, __builtin_amdgcn_rcpf(e2 + 1.f), a2);
            a3 = fmaf(n1.w, __builtin_amdgcn_rcpf(e3 + 1.f), a3);
        }
        {
            float e0 = fast_exp2(q2.x + k2.x), e1 = fast_exp2(q2.y + k2.y);
            float e2 = fast_exp2(q2.z + k2.z), e3 = fast_exp2(q2.w + k2.w);
            a0 = fmaf(n2.x, __builtin_amdgcn_rcpf(e0 + 1.f), a0);
            a1 = fmaf(n2.y, __builtin_amdgcn_rcpf(e1 + 1.f), a1);
            a2 = fmaf(n2.z, __builtin_amdgcn_rcpf(e2 + 1.f), a2);
            a3 = fmaf(n2.w, __builtin_amdgcn_rcpf(e3 + 1.f), a3);
        }
        {
            float e0 = fast_exp2(q3.x + k3.x), e1 = fast_exp2(q3.y + k3.y);
            float e2 = fast_exp2(q3.z + k3.z), e3 = fast_exp2(q3.w + k3.w);
            a0 = fmaf(n3.x, __builtin_amdgcn_rcpf(e0 + 1.f), a0);
            a1 = fmaf(n3.y, __builtin_amdgcn_rcpf(e1 + 1.f), a1);
            a2 = fmaf(n3.z, __builtin_amdgcn_rcpf(e2 + 1.f), a2);
            a3 = fmaf(n3.w, __builtin_amdgcn_rcpf(e3 + 1.f), a3);
        }
        float acc = (a0 + a1) + (a2 + a3);
        acc += __shfl_xor(acc, 8);
        acc += __shfl_xor(acc, 4);
        acc += __shfl_xor(acc, 2);
        acc += __shfl_xor(acc, 1);
        if (hg == 0)
            srow[k] = (k < vl) ? acc : -1e6f;
    }
}

// ---------------------------------------------------------------------------
// softmax over K then out[b,q,:] = attn @ values[b]
// grid (B, Q/4), block 256: wave w owns row q = qt*4+w
// ---------------------------------------------------------------------------
__global__ __launch_bounds__(256) void attn_pv_kernel(
        const float* __restrict__ scores, const float* __restrict__ values,
        float* __restrict__ out) {
    __shared__ float p[4][KK];
    const int b    = blockIdx.x;
    const int qt   = blockIdx.y;
    const int lane = threadIdx.x & 63;
    const int wave = threadIdx.x >> 6;
    const int q    = qt * 4 + wave;

    const float* srow = scores + (size_t)(b*QQ + q) * KK;
    float4 s0 = *(const float4*)(srow + lane*8);
    float4 s1 = *(const float4*)(srow + lane*8 + 4);

    float m = fmaxf(fmaxf(fmaxf(s0.x, s0.y), fmaxf(s0.z, s0.w)),
                    fmaxf(fmaxf(s1.x, s1.y), fmaxf(s1.z, s1.w)));
    #pragma unroll
    for (int off = 32; off > 0; off >>= 1)
        m = fmaxf(m, __shfl_xor(m, off));

    float e[8];
    e[0] = __expf(s0.x - m); e[1] = __expf(s0.y - m);
    e[2] = __expf(s0.z - m); e[3] = __expf(s0.w - m);
    e[4] = __expf(s1.x - m); e[5] = __expf(s1.y - m);
    e[6] = __expf(s1.z - m); e[7] = __expf(s1.w - m);
    float sum = ((e[0]+e[1]) + (e[2]+e[3])) + ((e[4]+e[5]) + (e[6]+e[7]));
    #pragma unroll
    for (int off = 32; off > 0; off >>= 1)
        sum += __shfl_xor(sum, off);
    const float inv = 1.0f / sum;

    float4 p0 = make_float4(e[0]*inv, e[1]*inv, e[2]*inv, e[3]*inv);
    float4 p1 = make_float4(e[4]*inv, e[5]*inv, e[6]*inv, e[7]*inv);
    *(float4*)(&p[wave][lane*8])     = p0;
    *(float4*)(&p[wave][lane*8 + 4]) = p1;
    __syncthreads();

    const int d = lane * 4;
    const float* V = values + (size_t)b * KK * DD;
    float4 acc = make_float4(0.f, 0.f, 0.f, 0.f);
    #pragma unroll 8
    for (int k = 0; k < KK; ++k) {
        float4 v4 = *(const float4*)(V + (size_t)k * DD + d);
        float pw = p[wave][k];
        acc.x += pw * v4.x; acc.y += pw * v4.y;
        acc.z += pw * v4.z; acc.w += pw * v4.w;
    }
    *(float4*)(out + (size_t)(b*QQ + q) * DD + d) = acc;
}

extern "C" void kernel_launch(void* const* d_in, const int* in_sizes, int n_in,
                              void* d_out, int out_size, void* d_ws, size_t ws_size,
                              hipStream_t stream) {
    (void)in_sizes; (void)n_in; (void)out_size; (void)ws_size;
    const float* querys     = (const float*)d_in[0];
    const float* keys       = (const float*)d_in[1];
    const float* values     = (const float*)d_in[2];
    const int*   valid_lens = (const int*)d_in[3];
    const float* Wq         = (const float*)d_in[4];
    const float* Wk         = (const float*)d_in[5];
    const float* w_v        = (const float*)d_in[6];
    float* out = (float*)d_out;

    float* qf     = (float*)d_ws;                      // 1 MB  (pre-scaled by 2log2e)
    float* kfeat  = qf + (size_t)BB*QQ*HH;             // 8 MB  (pre-scaled by 2log2e)
    float* scores = kfeat + (size_t)BB*KK*HH;          // 2 MB

    proj_both<<<dim3(16 + BB*KK/64, HH/64), 256, 0, stream>>>(
        querys, Wq, qf, keys, Wk, kfeat);
    scores_kernel<<<dim3(BB, QQ, KSPL), 256, 0, stream>>>(
        qf, kfeat, w_v, valid_lens, scores);
    attn_pv_kernel<<<dim3(BB, QQ/4), 256, 0, stream>>>(scores, values, out);
}

// Round 3
// 67.393 us; speedup vs baseline: 1.5975x; 1.2706x over previous
//
#include <hip/hip_runtime.h>

#define BB 16
#define QQ 64
#define KK 512
#define DD 256
#define HH 256
#define KSPL 4

#define LOG2E2 2.88539008177792681f   // 2*log2(e): exp2(LOG2E2*x) = e^{2x}

__device__ __forceinline__ float fast_exp2(float x) {
#if __has_builtin(__builtin_amdgcn_exp2f)
    return __builtin_amdgcn_exp2f(x);
#else
    return exp2f(x);
#endif
}

// ---------------------------------------------------------------------------
// Both projections in one launch. Y = (X @ W) * 2log2e.
// 64x64 tile, 256 thr, 4x4/thread, K-step 32, A transposed in LDS (b128 reads).
// ---------------------------------------------------------------------------
__global__ __launch_bounds__(256) void proj_both(
        const float* __restrict__ Xq, const float* __restrict__ Wq, float* __restrict__ Yq,
        const float* __restrict__ Xk, const float* __restrict__ Wk, float* __restrict__ Yk) {
    __shared__ float XsT[32][68];
    __shared__ float Ws[32][64];
    const int rt = blockIdx.x;
    const float* X; const float* W; float* Y; int row0;
    if (rt < 16) { X = Xq; W = Wq; Y = Yq; row0 = rt * 64; }
    else         { X = Xk; W = Wk; Y = Yk; row0 = (rt - 16) * 64; }
    const int col0 = blockIdx.y * 64;
    const int tid = threadIdx.x;
    const int tx = tid & 15, ty = tid >> 4;

    float acc[4][4] = {};

    for (int k0 = 0; k0 < HH; k0 += 32) {
        {
            const int m  = tid >> 3;
            const int kk = (tid & 7) * 4;
            #pragma unroll
            for (int s = 0; s < 2; ++s) {
                float4 x4 = *(const float4*)(X + (size_t)(row0 + m + 32*s) * HH + k0 + kk);
                XsT[kk+0][m+32*s] = x4.x;
                XsT[kk+1][m+32*s] = x4.y;
                XsT[kk+2][m+32*s] = x4.z;
                XsT[kk+3][m+32*s] = x4.w;
            }
        }
        {
            const int kk = tid >> 4;
            const int c  = (tid & 15) * 4;
            #pragma unroll
            for (int s = 0; s < 2; ++s) {
                float4 w4 = *(const float4*)(W + (size_t)(k0 + kk + 16*s) * HH + col0 + c);
                *(float4*)(&Ws[kk+16*s][c]) = w4;
            }
        }
        __syncthreads();
        #pragma unroll
        for (int kk = 0; kk < 32; ++kk) {
            float4 a = *(const float4*)(&XsT[kk][ty*4]);
            float4 b = *(const float4*)(&Ws[kk][tx*4]);
            acc[0][0] += a.x*b.x; acc[0][1] += a.x*b.y; acc[0][2] += a.x*b.z; acc[0][3] += a.x*b.w;
            acc[1][0] += a.y*b.x; acc[1][1] += a.y*b.y; acc[1][2] += a.y*b.z; acc[1][3] += a.y*b.w;
            acc[2][0] += a.z*b.x; acc[2][1] += a.z*b.y; acc[2][2] += a.z*b.z; acc[2][3] += a.z*b.w;
            acc[3][0] += a.w*b.x; acc[3][1] += a.w*b.y; acc[3][2] += a.w*b.z; acc[3][3] += a.w*b.w;
        }
        __syncthreads();
    }
    #pragma unroll
    for (int i = 0; i < 4; ++i) {
        float4 o = make_float4(acc[i][0]*LOG2E2, acc[i][1]*LOG2E2,
                               acc[i][2]*LOG2E2, acc[i][3]*LOG2E2);
        *(float4*)(Y + (size_t)(row0 + ty*4 + i) * HH + col0 + tx*4) = o;
    }
}

// ---------------------------------------------------------------------------
// scores for 2 q rows per block, with wave-uniform vl skip + k prefetch.
// Lane layout: hg = lane&15 owns h-chunk [hg*16, +16); ksub = lane>>4.
// grid (B, Q/2, KSPL), block 256 (4 waves); wave handles 32 k = 8 groups of 4.
// ---------------------------------------------------------------------------
__device__ __forceinline__ float score_partial(const float4 qv[4], const float4 kv[4],
                                               const float4 nw[4], float wvsum) {
    float a0 = wvsum, a1 = 0.f, a2 = 0.f, a3 = 0.f;
    #pragma unroll
    for (int i = 0; i < 4; ++i) {
        float e0 = fast_exp2(qv[i].x + kv[i].x);
        float e1 = fast_exp2(qv[i].y + kv[i].y);
        float e2 = fast_exp2(qv[i].z + kv[i].z);
        float e3 = fast_exp2(qv[i].w + kv[i].w);
        a0 = fmaf(nw[i].x, __builtin_amdgcn_rcpf(e0 + 1.f), a0);
        a1 = fmaf(nw[i].y, __builtin_amdgcn_rcpf(e1 + 1.f), a1);
        a2 = fmaf(nw[i].z, __builtin_amdgcn_rcpf(e2 + 1.f), a2);
        a3 = fmaf(nw[i].w, __builtin_amdgcn_rcpf(e3 + 1.f), a3);
    }
    return (a0 + a1) + (a2 + a3);
}

__global__ __launch_bounds__(256) void scores_kernel(
        const float* __restrict__ qf, const float* __restrict__ kf,
        const float* __restrict__ w_v, const int* __restrict__ valid_lens,
        float* __restrict__ scores) {
    const int b    = blockIdx.x;
    const int q0   = blockIdx.y * 2;
    const int ks   = blockIdx.z;
    const int lane = threadIdx.x & 63;
    const int wave = threadIdx.x >> 6;
    const int hg   = lane & 15;
    const int ksub = lane >> 4;
    const int h0   = hg * 16;

    float4 nw[4];
    float wvsum = 0.f;
    #pragma unroll
    for (int i = 0; i < 4; ++i) {
        float4 w = *(const float4*)(w_v + h0 + i*4);
        wvsum += ((w.x + w.y) + (w.z + w.w));
        nw[i] = make_float4(-2.f*w.x, -2.f*w.y, -2.f*w.z, -2.f*w.w);
    }

    float4 qA[4], qB[4];
    {
        const float* qrA = qf + (size_t)(b*QQ + q0) * HH + h0;
        const float* qrB = qrA + HH;
        #pragma unroll
        for (int i = 0; i < 4; ++i) {
            qA[i] = *(const float4*)(qrA + i*4);
            qB[i] = *(const float4*)(qrB + i*4);
        }
    }

    const int vl    = valid_lens[b];
    const int wbase = ks * (KK/KSPL) + wave * 32;
    int nact = vl - wbase;
    nact = (nact <= 0) ? 0 : ((nact >= 32) ? 8 : ((nact + 3) >> 2));

    float* srowA = scores + (size_t)(b*QQ + q0) * KK;
    float* srowB = srowA + KK;
    const float* kbase_ptr = kf + (size_t)(b*KK + wbase + ksub) * HH + h0;

    float4 kcur[4];
    if (nact > 0) {
        #pragma unroll
        for (int i = 0; i < 4; ++i) kcur[i] = *(const float4*)(kbase_ptr + i*4);
    }

    for (int g = 0; g < nact; ++g) {
        float4 knxt[4];
        if (g + 1 < nact) {
            const float* kp = kbase_ptr + (size_t)(g+1) * 4 * HH;
            #pragma unroll
            for (int i = 0; i < 4; ++i) knxt[i] = *(const float4*)(kp + i*4);
        } else {
            #pragma unroll
            for (int i = 0; i < 4; ++i) knxt[i] = kcur[i];
        }

        float sA = score_partial(qA, kcur, nw, wvsum);
        float sB = score_partial(qB, kcur, nw, wvsum);
        #pragma unroll
        for (int off = 8; off; off >>= 1) {
            sA += __shfl_xor(sA, off);
            sB += __shfl_xor(sB, off);
        }
        const int k = wbase + g*4 + ksub;
        if (hg == 0) {
            srowA[k] = (k < vl) ? sA : -1e6f;
            srowB[k] = (k < vl) ? sB : -1e6f;
        }
        #pragma unroll
        for (int i = 0; i < 4; ++i) kcur[i] = knxt[i];
    }
    for (int g = nact; g < 8; ++g) {
        const int k = wbase + g*4 + ksub;
        if (hg == 0) { srowA[k] = -1e6f; srowB[k] = -1e6f; }
    }
}

// ---------------------------------------------------------------------------
// softmax + PV, one block per (b,q): 4 waves split K; vl-limited PV;
// cross-wave reduce in LDS.
// ---------------------------------------------------------------------------
__global__ __launch_bounds__(256) void attn_pv_kernel(
        const float* __restrict__ scores, const float* __restrict__ values,
        const int* __restrict__ valid_lens, float* __restrict__ out) {
    __shared__ float ps[KK];
    __shared__ float red[4][DD];
    __shared__ float wred[8];
    const int b    = blockIdx.x;
    const int q    = blockIdx.y;
    const int tid  = threadIdx.x;
    const int lane = tid & 63;
    const int wave = tid >> 6;
    const int vl   = valid_lens[b];

    const float* srow = scores + (size_t)(b*QQ + q) * KK;
    float2 s = *(const float2*)(srow + wave*128 + lane*2);

    float m = fmaxf(s.x, s.y);
    #pragma unroll
    for (int off = 32; off; off >>= 1) m = fmaxf(m, __shfl_xor(m, off));
    if (lane == 0) wred[wave] = m;
    __syncthreads();
    m = fmaxf(fmaxf(wred[0], wred[1]), fmaxf(wred[2], wred[3]));

    float e0 = __expf(s.x - m), e1 = __expf(s.y - m);
    float sum = e0 + e1;
    #pragma unroll
    for (int off = 32; off; off >>= 1) sum += __shfl_xor(sum, off);
    if (lane == 0) wred[4 + wave] = sum;
    __syncthreads();
    sum = (wred[4] + wred[5]) + (wred[6] + wred[7]);
    const float inv = 1.f / sum;

    *(float2*)(&ps[wave*128 + lane*2]) = make_float2(e0*inv, e1*inv);
    __syncthreads();

    const int k0 = wave * 128;
    int kcnt = vl - k0;
    kcnt = (kcnt < 0) ? 0 : ((kcnt > 128) ? 128 : kcnt);

    float4 acc = make_float4(0.f, 0.f, 0.f, 0.f);
    const float* V = values + ((size_t)b*KK + k0) * DD + lane*4;
    #pragma unroll 4
    for (int k = 0; k < kcnt; ++k) {
        float pw = ps[k0 + k];
        float4 v4 = *(const float4*)(V + (size_t)k * DD);
        acc.x += pw * v4.x; acc.y += pw * v4.y;
        acc.z += pw * v4.z; acc.w += pw * v4.w;
    }
    *(float4*)(&red[wave][lane*4]) = acc;
    __syncthreads();

    const float o = red[0][tid] + red[1][tid] + red[2][tid] + red[3][tid];
    out[(size_t)(b*QQ + q) * DD + tid] = o;
}

extern "C" void kernel_launch(void* const* d_in, const int* in_sizes, int n_in,
                              void* d_out, int out_size, void* d_ws, size_t ws_size,
                              hipStream_t stream) {
    (void)in_sizes; (void)n_in; (void)out_size; (void)ws_size;
    const float* querys     = (const float*)d_in[0];
    const float* keys       = (const float*)d_in[1];
    const float* values     = (const float*)d_in[2];
    const int*   valid_lens = (const int*)d_in[3];
    const float* Wq         = (const float*)d_in[4];
    const float* Wk         = (const float*)d_in[5];
    const float* w_v        = (const float*)d_in[6];
    float* out = (float*)d_out;

    float* qf     = (float*)d_ws;                      // 1 MB (pre-scaled by 2log2e)
    float* kfeat  = qf + (size_t)BB*QQ*HH;             // 8 MB (pre-scaled by 2log2e)
    float* scores = kfeat + (size_t)BB*KK*HH;          // 2 MB

    proj_both<<<dim3(16 + BB*KK/64, HH/64), 256, 0, stream>>>(
        querys, Wq, qf, keys, Wk, kfeat);
    scores_kernel<<<dim3(BB, QQ/2, KSPL), 256, 0, stream>>>(
        qf, kfeat, w_v, valid_lens, scores);
    attn_pv_kernel<<<dim3(BB, QQ), 256, 0, stream>>>(
        scores, values, valid_lens, out);
}